// Round 1
// baseline (1195.100 us; speedup 1.0000x reference)
//
#include <hip/hip_runtime.h>
#include <hip/hip_bf16.h>

#define NN 100000
#define EE 1600000

typedef __attribute__((ext_vector_type(8))) short bf16x8;
typedef __attribute__((ext_vector_type(4))) float f32x4;
typedef __attribute__((ext_vector_type(4))) unsigned int u32x4;

__device__ __forceinline__ unsigned int f2bf(float x) {
    union { float f; unsigned int u; } v; v.f = x;
    return (v.u + 0x7fffu + ((v.u >> 16) & 1u)) >> 16;
}
__device__ __forceinline__ unsigned int pack2(float a, float b) {
    return f2bf(a) | (f2bf(b) << 16);
}

__global__ void k_deg(const int* __restrict__ dst, float* __restrict__ deg) {
    int e = blockIdx.x * 256 + threadIdx.x;
    if (e < EE) atomicAdd(&deg[dst[e]], 1.0f);
}

__global__ void k_inv(const float* __restrict__ deg, float* __restrict__ inv) {
    int n = blockIdx.x * 256 + threadIdx.x;
    if (n < NN) { float d = deg[n]; inv[n] = (d > 0.f) ? (1.f / d) : 0.f; }
}

// Pack W (K x NOUT, row-major f32) into B-fragment order:
// pW[((nt*KC)+kc)*64 + lane] = 8 bf16 at k = kc*32 + (lane>>4)*8 + j, n = nt*16 + (lane&15)
__global__ void k_packW(const float* __restrict__ W, u32x4* __restrict__ pW,
                        int KC, int NT, int NOUT) {
    int g = blockIdx.x * 256 + threadIdx.x;
    if (g >= NT * KC * 64) return;
    int lane = g & 63;
    int rest = g >> 6;
    int kc = rest % KC;
    int nt = rest / KC;
    int k0 = kc * 32 + ((lane >> 4) << 3);
    int n  = nt * 16 + (lane & 15);
    u32x4 u;
    #pragma unroll
    for (int t = 0; t < 4; ++t)
        u[t] = pack2(W[(k0 + 2 * t) * NOUT + n], W[(k0 + 2 * t + 1) * NOUT + n]);
    pW[g] = u;
}

// PHASE 0: L1 msg (edge):  A=[nfeats[src], e]        K=128 -> atomic agg1 (NOUT=128)
// PHASE 1: L1 apply (node):A=[nfeats, agg1*inv+b1m]  K=192 -> relu+b1a -> x1 bf16 (NOUT=128)
// PHASE 2: L2 msg (edge):  A=[x1[src], e]            K=192 -> atomic agg2 (NOUT=64)
// PHASE 3: L2 apply (node):A=[x1, agg2*inv+b2m]      K=192 -> relu+b2a -> out f32 (NOUT=64)
template<int K, int NOUT, int PHASE>
__global__ __launch_bounds__(256, 2)
void k_gemm(const float* __restrict__ nfeats, const float* __restrict__ efeats,
            const int* __restrict__ src, const int* __restrict__ dst,
            const unsigned short* __restrict__ x1,
            const float* __restrict__ aggIn, const float* __restrict__ invdeg,
            const float* __restrict__ bpre, const float* __restrict__ bpost,
            const u32x4* __restrict__ pW,
            float* __restrict__ aggOut, unsigned short* __restrict__ x1out,
            float* __restrict__ out)
{
    constexpr int KC = K / 32;       // 32-k MFMA chunks
    constexpr int U  = K / 8;        // 16B units per row
    constexpr int CH = K / 16;       // 16-elem staging chunks per row
    constexpr int NT = (NOUT == 128) ? 4 : 2;  // n-tiles per wave
    constexpr bool EDGE = (PHASE == 0) || (PHASE == 2);

    __shared__ u32x4 A4[128 * U];
    __shared__ int dstl[128];

    const int tid  = threadIdx.x;
    const int lane = tid & 63;
    const int w    = tid >> 6;
    const int tileM = blockIdx.x * 128;

    if (EDGE && tid < 128) dstl[tid] = dst[tileM + tid];

    // ---- stage A tile (128 rows x K) into swizzled LDS as bf16 ----
    for (int idx = tid; idx < 128 * CH; idx += 256) {
        const int row = idx / CH;
        const int c   = idx - row * CH;
        const int k0  = c * 16;
        const int gr  = tileM + row;
        u32x4 u0, u1;
        u0[0]=u0[1]=u0[2]=u0[3]=0u; u1[0]=u1[1]=u1[2]=u1[3]=0u;

        if constexpr (PHASE == 0) {
            const float* p = (k0 < 64) ? (nfeats + (size_t)src[gr] * 64 + k0)
                                       : (efeats + (size_t)gr * 64 + (k0 - 64));
            const f32x4* pv = (const f32x4*)p;
            f32x4 f0 = pv[0], f1 = pv[1], f2 = pv[2], f3 = pv[3];
            u0[0]=pack2(f0[0],f0[1]); u0[1]=pack2(f0[2],f0[3]);
            u0[2]=pack2(f1[0],f1[1]); u0[3]=pack2(f1[2],f1[3]);
            u1[0]=pack2(f2[0],f2[1]); u1[1]=pack2(f2[2],f2[3]);
            u1[2]=pack2(f3[0],f3[1]); u1[3]=pack2(f3[2],f3[3]);
        } else if constexpr (PHASE == 2) {
            if (k0 < 128) {
                const u32x4* p = (const u32x4*)(x1 + (size_t)src[gr] * 128 + k0);
                u0 = p[0]; u1 = p[1];
            } else {
                const f32x4* pv = (const f32x4*)(efeats + (size_t)gr * 64 + (k0 - 128));
                f32x4 f0 = pv[0], f1 = pv[1], f2 = pv[2], f3 = pv[3];
                u0[0]=pack2(f0[0],f0[1]); u0[1]=pack2(f0[2],f0[3]);
                u0[2]=pack2(f1[0],f1[1]); u0[3]=pack2(f1[2],f1[3]);
                u1[0]=pack2(f2[0],f2[1]); u1[1]=pack2(f2[2],f2[3]);
                u1[2]=pack2(f3[0],f3[1]); u1[3]=pack2(f3[2],f3[3]);
            }
        } else {
            const bool ok = (gr < NN);
            if (ok) {
                if constexpr (PHASE == 1) {
                    if (k0 < 64) {
                        const f32x4* pv = (const f32x4*)(nfeats + (size_t)gr * 64 + k0);
                        f32x4 f0 = pv[0], f1 = pv[1], f2 = pv[2], f3 = pv[3];
                        u0[0]=pack2(f0[0],f0[1]); u0[1]=pack2(f0[2],f0[3]);
                        u0[2]=pack2(f1[0],f1[1]); u0[3]=pack2(f1[2],f1[3]);
                        u1[0]=pack2(f2[0],f2[1]); u1[1]=pack2(f2[2],f2[3]);
                        u1[2]=pack2(f3[0],f3[1]); u1[3]=pack2(f3[2],f3[3]);
                    } else {
                        const int j0 = k0 - 64;
                        const float iv  = invdeg[gr];
                        const float msk = (iv > 0.f) ? 1.f : 0.f;
                        const f32x4* pa = (const f32x4*)(aggIn + (size_t)gr * 128 + j0);
                        const f32x4* pb = (const f32x4*)(bpre + j0);
                        f32x4 g[4];
                        #pragma unroll
                        for (int t = 0; t < 4; ++t) {
                            f32x4 a = pa[t], b = pb[t];
                            #pragma unroll
                            for (int q = 0; q < 4; ++q) g[t][q] = a[q] * iv + b[q] * msk;
                        }
                        u0[0]=pack2(g[0][0],g[0][1]); u0[1]=pack2(g[0][2],g[0][3]);
                        u0[2]=pack2(g[1][0],g[1][1]); u0[3]=pack2(g[1][2],g[1][3]);
                        u1[0]=pack2(g[2][0],g[2][1]); u1[1]=pack2(g[2][2],g[2][3]);
                        u1[2]=pack2(g[3][0],g[3][1]); u1[3]=pack2(g[3][2],g[3][3]);
                    }
                } else { // PHASE 3
                    if (k0 < 128) {
                        const u32x4* p = (const u32x4*)(x1 + (size_t)gr * 128 + k0);
                        u0 = p[0]; u1 = p[1];
                    } else {
                        const int j0 = k0 - 128;
                        const float iv  = invdeg[gr];
                        const float msk = (iv > 0.f) ? 1.f : 0.f;
                        const f32x4* pa = (const f32x4*)(aggIn + (size_t)gr * 64 + j0);
                        const f32x4* pb = (const f32x4*)(bpre + j0);
                        f32x4 g[4];
                        #pragma unroll
                        for (int t = 0; t < 4; ++t) {
                            f32x4 a = pa[t], b = pb[t];
                            #pragma unroll
                            for (int q = 0; q < 4; ++q) g[t][q] = a[q] * iv + b[q] * msk;
                        }
                        u0[0]=pack2(g[0][0],g[0][1]); u0[1]=pack2(g[0][2],g[0][3]);
                        u0[2]=pack2(g[1][0],g[1][1]); u0[3]=pack2(g[1][2],g[1][3]);
                        u1[0]=pack2(g[2][0],g[2][1]); u1[1]=pack2(g[2][2],g[2][3]);
                        u1[2]=pack2(g[3][0],g[3][1]); u1[3]=pack2(g[3][2],g[3][3]);
                    }
                }
            }
        }
        const int q = k0 >> 3;      // 16B unit index in row
        const int s = row & 7;      // XOR swizzle (T2 / G4)
        A4[row * U + ((q    ) ^ s)] = u0;
        A4[row * U + ((q + 1) ^ s)] = u1;
    }
    __syncthreads();

    // ---- MFMA: wave tile = 64 rows x (NT*16) cols ----
    const int rowBase = (w >> 1) * 64;
    const int ctBase  = (w & 1) * NT;
    const int lrow    = lane & 15;
    const int kq      = lane >> 4;

    f32x4 acc[4][NT];
    #pragma unroll
    for (int mt = 0; mt < 4; ++mt)
        #pragma unroll
        for (int nt = 0; nt < NT; ++nt)
            #pragma unroll
            for (int q = 0; q < 4; ++q) acc[mt][nt][q] = 0.f;

    for (int kc = 0; kc < KC; ++kc) {
        bf16x8 a[4];
        #pragma unroll
        for (int mt = 0; mt < 4; ++mt) {
            const int row = rowBase + mt * 16 + lrow;
            a[mt] = __builtin_bit_cast(bf16x8, A4[row * U + ((kc * 4 + kq) ^ (row & 7))]);
        }
        #pragma unroll
        for (int nt = 0; nt < NT; ++nt) {
            bf16x8 b = __builtin_bit_cast(bf16x8,
                        pW[(size_t)((ctBase + nt) * KC + kc) * 64 + lane]);
            #pragma unroll
            for (int mt = 0; mt < 4; ++mt)
                acc[mt][nt] = __builtin_amdgcn_mfma_f32_16x16x32_bf16(a[mt], b, acc[mt][nt], 0, 0, 0);
        }
    }

    // ---- epilogue ----
    if constexpr (EDGE) {
        #pragma unroll
        for (int mt = 0; mt < 4; ++mt) {
            #pragma unroll
            for (int j = 0; j < 4; ++j) {
                const int rl = rowBase + mt * 16 + (lane >> 4) * 4 + j;
                const int d  = dstl[rl];
                float* base = aggOut + (size_t)d * NOUT;
                #pragma unroll
                for (int nt = 0; nt < NT; ++nt)
                    atomicAdd(base + (ctBase + nt) * 16 + lrow, acc[mt][nt][j]);
            }
        }
    } else {
        float bb[NT];
        #pragma unroll
        for (int nt = 0; nt < NT; ++nt) bb[nt] = bpost[(ctBase + nt) * 16 + lrow];
        #pragma unroll
        for (int mt = 0; mt < 4; ++mt) {
            #pragma unroll
            for (int j = 0; j < 4; ++j) {
                const int gr = tileM + rowBase + mt * 16 + (lane >> 4) * 4 + j;
                if (gr < NN) {
                    #pragma unroll
                    for (int nt = 0; nt < NT; ++nt) {
                        float v = acc[mt][nt][j] + bb[nt];
                        v = fmaxf(v, 0.f);
                        const int col = (ctBase + nt) * 16 + lrow;
                        if constexpr (PHASE == 1)
                            x1out[(size_t)gr * 128 + col] = (unsigned short)f2bf(v);
                        else
                            out[(size_t)gr * 64 + col] = v;
                    }
                }
            }
        }
    }
}

extern "C" void kernel_launch(void* const* d_in, const int* in_sizes, int n_in,
                              void* d_out, int out_size, void* d_ws, size_t ws_size,
                              hipStream_t stream) {
    const float* nfeats = (const float*)d_in[0];
    const float* efeats = (const float*)d_in[1];
    const int*   src    = (const int*)d_in[2];
    const int*   dst    = (const int*)d_in[3];
    const float* W1m = (const float*)d_in[4];
    const float* b1m = (const float*)d_in[5];
    const float* W1a = (const float*)d_in[6];
    const float* b1a = (const float*)d_in[7];
    const float* W2m = (const float*)d_in[8];
    const float* b2m = (const float*)d_in[9];
    const float* W2a = (const float*)d_in[10];
    const float* b2a = (const float*)d_in[11];
    float* out = (float*)d_out;

    char* ws = (char*)d_ws;
    float*          agg1 = (float*)(ws + 0);                    // N*128 f32 = 51.2 MB
    float*          agg2 = (float*)(ws + 51200000);             // N*64  f32 = 25.6 MB
    unsigned short* x1   = (unsigned short*)(ws + 76800000);    // N*128 bf16 = 25.6 MB
    float*          deg  = (float*)(ws + 102400000);            // N f32
    float*          inv  = (float*)(ws + 102800000);            // N f32
    u32x4* pW1m = (u32x4*)(ws + 103200000);                     // 32 KB
    u32x4* pW1a = (u32x4*)(ws + 103232768);                     // 48 KB
    u32x4* pW2m = (u32x4*)(ws + 103281920);                     // 24 KB
    u32x4* pW2a = (u32x4*)(ws + 103306496);                     // 24 KB

    hipMemsetAsync(agg1, 0, (size_t)NN * 128 * 4, stream);
    hipMemsetAsync(agg2, 0, (size_t)NN * 64 * 4, stream);
    hipMemsetAsync(deg,  0, (size_t)NN * 4, stream);

    k_deg<<<(EE + 255) / 256, 256, 0, stream>>>(dst, deg);
    k_inv<<<(NN + 255) / 256, 256, 0, stream>>>(deg, inv);

    k_packW<<<(2048 + 255) / 256, 256, 0, stream>>>(W1m, pW1m, 4, 8, 128);
    k_packW<<<(3072 + 255) / 256, 256, 0, stream>>>(W1a, pW1a, 6, 8, 128);
    k_packW<<<(1536 + 255) / 256, 256, 0, stream>>>(W2m, pW2m, 6, 4, 64);
    k_packW<<<(1536 + 255) / 256, 256, 0, stream>>>(W2a, pW2a, 6, 4, 64);

    // L1 msg: edges, K=128, NOUT=128 -> agg1
    k_gemm<128,128,0><<<EE / 128, 256, 0, stream>>>(nfeats, efeats, src, dst,
        nullptr, nullptr, nullptr, nullptr, nullptr, pW1m, agg1, nullptr, nullptr);
    // L1 apply: nodes, K=192, NOUT=128 -> x1 (bf16)
    k_gemm<192,128,1><<<(NN + 127) / 128, 256, 0, stream>>>(nfeats, efeats, src, dst,
        nullptr, agg1, inv, b1m, b1a, pW1a, nullptr, x1, nullptr);
    // L2 msg: edges, K=192, NOUT=64 -> agg2
    k_gemm<192,64,2><<<EE / 128, 256, 0, stream>>>(nfeats, efeats, src, dst,
        x1, nullptr, nullptr, nullptr, nullptr, pW2m, agg2, nullptr, nullptr);
    // L2 apply: nodes, K=192, NOUT=64 -> out (f32)
    k_gemm<192,64,3><<<(NN + 127) / 128, 256, 0, stream>>>(nfeats, efeats, src, dst,
        x1, agg2, inv, b2m, b2a, pW2a, nullptr, nullptr, out);
}

// Round 2
// 1110.209 us; speedup vs baseline: 1.0765x; 1.0765x over previous
//
#include <hip/hip_runtime.h>
#include <hip/hip_bf16.h>

#define NN 100000
#define EE 1600000
#define NB_SCAN 391   // (NN+255)/256

typedef __attribute__((ext_vector_type(8))) short bf16x8;
typedef __attribute__((ext_vector_type(4))) float f32x4;
typedef __attribute__((ext_vector_type(4))) unsigned int u32x4;

__device__ __forceinline__ unsigned int f2bf(float x) {
    union { float f; unsigned int u; } v; v.f = x;
    return (v.u + 0x7fffu + ((v.u >> 16) & 1u)) >> 16;
}
__device__ __forceinline__ unsigned int pack2(float a, float b) {
    return f2bf(a) | (f2bf(b) << 16);
}

// ---------------- CSR build: count -> exclusive scan -> scatter ----------------

__global__ void k_count(const int* __restrict__ dst, int* __restrict__ cnt) {
    int e = blockIdx.x * 256 + threadIdx.x;
    if (e < EE) atomicAdd(&cnt[dst[e]], 1);
}

__global__ void k_scan1(const int* __restrict__ cnt, int* __restrict__ offs,
                        int* __restrict__ part) {
    __shared__ int s[256];
    const int t = threadIdx.x;
    const int i = blockIdx.x * 256 + t;
    int v = (i < NN) ? cnt[i] : 0;
    s[t] = v; __syncthreads();
    for (int d = 1; d < 256; d <<= 1) {
        int o = (t >= d) ? s[t - d] : 0;
        __syncthreads();
        s[t] += o;
        __syncthreads();
    }
    if (i < NN) offs[i] = s[t] - v;            // exclusive
    if (t == 255) part[blockIdx.x] = s[255];   // block total
}

__global__ void k_scan2(int* __restrict__ part) {
    __shared__ int s[512];
    const int t = threadIdx.x;
    int v = (t < NB_SCAN) ? part[t] : 0;
    s[t] = v; __syncthreads();
    for (int d = 1; d < 512; d <<= 1) {
        int o = (t >= d) ? s[t - d] : 0;
        __syncthreads();
        s[t] += o;
        __syncthreads();
    }
    if (t < NB_SCAN) part[t] = s[t] - v;       // exclusive over partials
}

__global__ void k_scan3(const int* __restrict__ cnt, const int* __restrict__ offs,
                        const int* __restrict__ part, int* __restrict__ cur,
                        float* __restrict__ inv) {
    int i = blockIdx.x * 256 + threadIdx.x;
    if (i < NN) {
        cur[i] = offs[i] + part[blockIdx.x];
        int c = cnt[i];
        inv[i] = (c > 0) ? (1.0f / (float)c) : 0.0f;
    }
}

__global__ void k_scatter(const int* __restrict__ dst, int* __restrict__ cur,
                          int* __restrict__ eperm) {
    int e = blockIdx.x * 256 + threadIdx.x;
    if (e < EE) {
        int p = atomicAdd(&cur[dst[e]], 1);
        eperm[p] = e;
    }
}

// ---------------- weight pack (A/B fragment lane order is identical) ----------------
// pW[((nt*KC)+kc)*64 + lane] = 8 bf16 at k = kc*32 + (lane>>4)*8 + j, n = nt*16 + (lane&15)
__global__ void k_packW(const float* __restrict__ W, u32x4* __restrict__ pW,
                        int KC, int NT, int NOUT) {
    int g = blockIdx.x * 256 + threadIdx.x;
    if (g >= NT * KC * 64) return;
    int lane = g & 63;
    int rest = g >> 6;
    int kc = rest % KC;
    int nt = rest / KC;
    int k0 = kc * 32 + ((lane >> 4) << 3);
    int n  = nt * 16 + (lane & 15);
    u32x4 u;
    #pragma unroll
    for (int t = 0; t < 4; ++t)
        u[t] = pack2(W[(k0 + 2 * t) * NOUT + n], W[(k0 + 2 * t + 1) * NOUT + n]);
    pW[g] = u;
}

// PHASE 0: L1 msg (edge, CSR order):  A=W1m^T, B=[nfeats[src], e]^T  K=128, NOUT=128 -> seg-reduce -> agg1
// PHASE 1: L1 apply (node):           A=[nfeats, agg1*inv+b1m]       K=192, NOUT=128 -> relu -> x1 bf16
// PHASE 2: L2 msg (edge, CSR order):  A=W2m^T, B=[x1[src], e]^T      K=192, NOUT=64  -> seg-reduce -> agg2
// PHASE 3: L2 apply (node):           A=[x1, agg2*inv+b2m]           K=192, NOUT=64  -> relu -> out f32
template<int K, int NOUT, int PHASE>
__global__ __launch_bounds__(256, 2)
void k_gemm(const float* __restrict__ nfeats, const float* __restrict__ efeats,
            const int* __restrict__ src, const int* __restrict__ dst,
            const int* __restrict__ eperm,
            const unsigned short* __restrict__ x1,
            const float* __restrict__ aggIn, const float* __restrict__ invdeg,
            const float* __restrict__ bpre, const float* __restrict__ bpost,
            const u32x4* __restrict__ pW,
            float* __restrict__ aggOut, unsigned short* __restrict__ x1out,
            float* __restrict__ out)
{
    constexpr int KC = K / 32;       // 32-k MFMA chunks
    constexpr int U  = K / 8;        // 16B units per row
    constexpr int CH = K / 16;       // 16-elem staging chunks per row
    constexpr int NT = (NOUT == 128) ? 4 : 2;  // n-tiles per wave
    constexpr bool EDGE = (PHASE == 0) || (PHASE == 2);

    __shared__ u32x4 A4[128 * U];
    __shared__ int dstl[128];
    __shared__ int srcl[128];

    const int tid  = threadIdx.x;
    const int lane = tid & 63;
    const int w    = tid >> 6;
    const int tileM = blockIdx.x * 128;

    if constexpr (EDGE) {
        if (tid < 128) {
            const int ep = eperm[tileM + tid];
            dstl[tid] = dst[ep];
            srcl[tid] = src[ep];
            // stash ep in dstl's sibling? keep a 3rd array: reuse srcl for src, need ep for efeats.
        }
        __syncthreads();
    }
    // for edge phases we also need ep per row for efeats/x1 row addressing
    __shared__ int epl[128];
    if constexpr (EDGE) {
        if (tid < 128) epl[tid] = eperm[tileM + tid];
        __syncthreads();
    }

    // ---- stage tile (128 rows x K) into swizzled LDS as bf16 ----
    for (int idx = tid; idx < 128 * CH; idx += 256) {
        const int row = idx / CH;
        const int c   = idx - row * CH;
        const int k0  = c * 16;
        const int gr  = tileM + row;
        u32x4 u0, u1;
        u0[0]=u0[1]=u0[2]=u0[3]=0u; u1[0]=u1[1]=u1[2]=u1[3]=0u;

        if constexpr (PHASE == 0) {
            const float* p = (k0 < 64) ? (nfeats + (size_t)srcl[row] * 64 + k0)
                                       : (efeats + (size_t)epl[row] * 64 + (k0 - 64));
            const f32x4* pv = (const f32x4*)p;
            f32x4 f0 = pv[0], f1 = pv[1], f2 = pv[2], f3 = pv[3];
            u0[0]=pack2(f0[0],f0[1]); u0[1]=pack2(f0[2],f0[3]);
            u0[2]=pack2(f1[0],f1[1]); u0[3]=pack2(f1[2],f1[3]);
            u1[0]=pack2(f2[0],f2[1]); u1[1]=pack2(f2[2],f2[3]);
            u1[2]=pack2(f3[0],f3[1]); u1[3]=pack2(f3[2],f3[3]);
        } else if constexpr (PHASE == 2) {
            if (k0 < 128) {
                const u32x4* p = (const u32x4*)(x1 + (size_t)srcl[row] * 128 + k0);
                u0 = p[0]; u1 = p[1];
            } else {
                const f32x4* pv = (const f32x4*)(efeats + (size_t)epl[row] * 64 + (k0 - 128));
                f32x4 f0 = pv[0], f1 = pv[1], f2 = pv[2], f3 = pv[3];
                u0[0]=pack2(f0[0],f0[1]); u0[1]=pack2(f0[2],f0[3]);
                u0[2]=pack2(f1[0],f1[1]); u0[3]=pack2(f1[2],f1[3]);
                u1[0]=pack2(f2[0],f2[1]); u1[1]=pack2(f2[2],f2[3]);
                u1[2]=pack2(f3[0],f3[1]); u1[3]=pack2(f3[2],f3[3]);
            }
        } else {
            const bool ok = (gr < NN);
            if (ok) {
                constexpr int KSPLIT = (PHASE == 1) ? 64 : 128;
                if (k0 < KSPLIT) {
                    if constexpr (PHASE == 1) {
                        const f32x4* pv = (const f32x4*)(nfeats + (size_t)gr * 64 + k0);
                        f32x4 f0 = pv[0], f1 = pv[1], f2 = pv[2], f3 = pv[3];
                        u0[0]=pack2(f0[0],f0[1]); u0[1]=pack2(f0[2],f0[3]);
                        u0[2]=pack2(f1[0],f1[1]); u0[3]=pack2(f1[2],f1[3]);
                        u1[0]=pack2(f2[0],f2[1]); u1[1]=pack2(f2[2],f2[3]);
                        u1[2]=pack2(f3[0],f3[1]); u1[3]=pack2(f3[2],f3[3]);
                    } else {
                        const u32x4* p = (const u32x4*)(x1 + (size_t)gr * 128 + k0);
                        u0 = p[0]; u1 = p[1];
                    }
                } else {
                    const int j0 = k0 - KSPLIT;
                    const int NAGG = (PHASE == 1) ? 128 : 64;
                    const float iv  = invdeg[gr];
                    const float msk = (iv > 0.f) ? 1.f : 0.f;
                    const f32x4* pa = (const f32x4*)(aggIn + (size_t)gr * NAGG + j0);
                    const f32x4* pb = (const f32x4*)(bpre + j0);
                    f32x4 g[4];
                    #pragma unroll
                    for (int t = 0; t < 4; ++t) {
                        f32x4 a = pa[t], b = pb[t];
                        #pragma unroll
                        for (int q = 0; q < 4; ++q) g[t][q] = a[q] * iv + b[q] * msk;
                    }
                    u0[0]=pack2(g[0][0],g[0][1]); u0[1]=pack2(g[0][2],g[0][3]);
                    u0[2]=pack2(g[1][0],g[1][1]); u0[3]=pack2(g[1][2],g[1][3]);
                    u1[0]=pack2(g[2][0],g[2][1]); u1[1]=pack2(g[2][2],g[2][3]);
                    u1[2]=pack2(g[3][0],g[3][1]); u1[3]=pack2(g[3][2],g[3][3]);
                }
            }
        }
        const int q = k0 >> 3;      // 16B unit index in row
        const int s = row & 7;      // XOR swizzle (T2 / G4)
        A4[row * U + ((q    ) ^ s)] = u0;
        A4[row * U + ((q + 1) ^ s)] = u1;
    }
    __syncthreads();

    // ---- MFMA: wave tile = 64 rows x (NT*16) cols ----
    const int rowBase = (w >> 1) * 64;
    const int ctBase  = (w & 1) * NT;
    const int lrow    = lane & 15;
    const int kq      = lane >> 4;

    f32x4 acc[4][NT];
    #pragma unroll
    for (int mt = 0; mt < 4; ++mt)
        #pragma unroll
        for (int nt = 0; nt < NT; ++nt)
            #pragma unroll
            for (int q = 0; q < 4; ++q) acc[mt][nt][q] = 0.f;

    for (int kc = 0; kc < KC; ++kc) {
        bf16x8 a[4];
        #pragma unroll
        for (int mt = 0; mt < 4; ++mt) {
            const int row = rowBase + mt * 16 + lrow;
            a[mt] = __builtin_bit_cast(bf16x8, A4[row * U + ((kc * 4 + kq) ^ (row & 7))]);
        }
        #pragma unroll
        for (int nt = 0; nt < NT; ++nt) {
            bf16x8 b = __builtin_bit_cast(bf16x8,
                        pW[(size_t)((ctBase + nt) * KC + kc) * 64 + lane]);
            #pragma unroll
            for (int mt = 0; mt < 4; ++mt) {
                if constexpr (EDGE)
                    // transposed: D[f, e] -> edges along lane&15 (sorted by dst)
                    acc[mt][nt] = __builtin_amdgcn_mfma_f32_16x16x32_bf16(b, a[mt], acc[mt][nt], 0, 0, 0);
                else
                    acc[mt][nt] = __builtin_amdgcn_mfma_f32_16x16x32_bf16(a[mt], b, acc[mt][nt], 0, 0, 0);
            }
        }
    }

    // ---- epilogue ----
    if constexpr (EDGE) {
        // acc[mt][nt]: col = lane&15 = edge (mt*16 group), row = (lane>>4)*4+j = feature in tile ctBase+nt
        // edges sorted by dst -> segmented inclusive scan over 16 lanes, tails flush atomically
        #pragma unroll
        for (int mt = 0; mt < 4; ++mt) {
            const int el  = rowBase + mt * 16 + lrow;
            const int key = dstl[el];
            #pragma unroll
            for (int d = 1; d < 16; d <<= 1) {
                const bool take = (lrow >= d) && (dstl[(el - d) & 127] == key);
                #pragma unroll
                for (int nt = 0; nt < NT; ++nt)
                    #pragma unroll
                    for (int j = 0; j < 4; ++j) {
                        float o = __shfl_up(acc[mt][nt][j], (unsigned)d, 16);
                        if (take) acc[mt][nt][j] += o;
                    }
            }
            const bool tail = (lrow == 15) || (dstl[el + 1] != key);
            if (tail) {
                float* base = aggOut + (size_t)key * NOUT;
                #pragma unroll
                for (int nt = 0; nt < NT; ++nt)
                    #pragma unroll
                    for (int j = 0; j < 4; ++j)
                        atomicAdd(base + (ctBase + nt) * 16 + kq * 4 + j, acc[mt][nt][j]);
            }
        }
    } else {
        float bb[NT];
        #pragma unroll
        for (int nt = 0; nt < NT; ++nt) bb[nt] = bpost[(ctBase + nt) * 16 + lrow];
        #pragma unroll
        for (int mt = 0; mt < 4; ++mt) {
            #pragma unroll
            for (int j = 0; j < 4; ++j) {
                const int gr = tileM + rowBase + mt * 16 + kq * 4 + j;
                if (gr < NN) {
                    #pragma unroll
                    for (int nt = 0; nt < NT; ++nt) {
                        float v = acc[mt][nt][j] + bb[nt];
                        v = fmaxf(v, 0.f);
                        const int col = (ctBase + nt) * 16 + lrow;
                        if constexpr (PHASE == 1)
                            x1out[(size_t)gr * 128 + col] = (unsigned short)f2bf(v);
                        else
                            out[(size_t)gr * 64 + col] = v;
                    }
                }
            }
        }
    }
}

extern "C" void kernel_launch(void* const* d_in, const int* in_sizes, int n_in,
                              void* d_out, int out_size, void* d_ws, size_t ws_size,
                              hipStream_t stream) {
    const float* nfeats = (const float*)d_in[0];
    const float* efeats = (const float*)d_in[1];
    const int*   src    = (const int*)d_in[2];
    const int*   dst    = (const int*)d_in[3];
    const float* W1m = (const float*)d_in[4];
    const float* b1m = (const float*)d_in[5];
    const float* W1a = (const float*)d_in[6];
    const float* b1a = (const float*)d_in[7];
    const float* W2m = (const float*)d_in[8];
    const float* b2m = (const float*)d_in[9];
    const float* W2a = (const float*)d_in[10];
    const float* b2a = (const float*)d_in[11];
    float* out = (float*)d_out;

    char* ws = (char*)d_ws;
    float*          agg1 = (float*)(ws + 0);                    // N*128 f32 = 51.2 MB
    float*          agg2 = (float*)(ws + 0);                    // overlays agg1 (dead after phase 1)
    unsigned short* x1   = (unsigned short*)(ws + 51200000);    // N*128 bf16 = 25.6 MB
    int*            eperm= (int*)(ws + 76800000);               // E int = 6.4 MB
    int*            cnt  = (int*)(ws + 83200000);               // N int
    int*            offs = (int*)(ws + 83600000);               // N int
    int*            cur  = (int*)(ws + 84000000);               // N int
    int*            part = (int*)(ws + 84400000);               // 512 int
    float*          inv  = (float*)(ws + 84402048);             // N f32
    u32x4* pW1m = (u32x4*)(ws + 84802048);                      // 32 KB
    u32x4* pW1a = (u32x4*)(ws + 84834816);                      // 48 KB
    u32x4* pW2m = (u32x4*)(ws + 84883968);                      // 24 KB
    u32x4* pW2a = (u32x4*)(ws + 84908544);                      // 24 KB

    hipMemsetAsync(agg1, 0, (size_t)NN * 128 * 4, stream);
    hipMemsetAsync(cnt,  0, (size_t)NN * 4, stream);

    k_packW<<<(2048 + 255) / 256, 256, 0, stream>>>(W1m, pW1m, 4, 8, 128);
    k_packW<<<(3072 + 255) / 256, 256, 0, stream>>>(W1a, pW1a, 6, 8, 128);
    k_packW<<<(1536 + 255) / 256, 256, 0, stream>>>(W2m, pW2m, 6, 4, 64);
    k_packW<<<(1536 + 255) / 256, 256, 0, stream>>>(W2a, pW2a, 6, 4, 64);

    // CSR bucketing by dst
    k_count  <<<(EE + 255) / 256, 256, 0, stream>>>(dst, cnt);
    k_scan1  <<<NB_SCAN, 256, 0, stream>>>(cnt, offs, part);
    k_scan2  <<<1, 512, 0, stream>>>(part);
    k_scan3  <<<NB_SCAN, 256, 0, stream>>>(cnt, offs, part, cur, inv);
    k_scatter<<<(EE + 255) / 256, 256, 0, stream>>>(dst, cur, eperm);

    // L1 msg: edges (CSR order), K=128, NOUT=128 -> agg1
    k_gemm<128,128,0><<<EE / 128, 256, 0, stream>>>(nfeats, efeats, src, dst, eperm,
        nullptr, nullptr, nullptr, nullptr, nullptr, pW1m, agg1, nullptr, nullptr);
    // L1 apply: nodes, K=192, NOUT=128 -> x1 (bf16)
    k_gemm<192,128,1><<<(NN + 127) / 128, 256, 0, stream>>>(nfeats, efeats, src, dst, eperm,
        nullptr, agg1, inv, b1m, b1a, pW1a, nullptr, x1, nullptr);
    // zero agg2 (overlays agg1; stream order guarantees phase 1 is done)
    hipMemsetAsync(agg2, 0, (size_t)NN * 64 * 4, stream);
    // L2 msg: edges (CSR order), K=192, NOUT=64 -> agg2
    k_gemm<192,64,2><<<EE / 128, 256, 0, stream>>>(nfeats, efeats, src, dst, eperm,
        x1, nullptr, nullptr, nullptr, nullptr, pW2m, agg2, nullptr, nullptr);
    // L2 apply: nodes, K=192, NOUT=64 -> out (f32)
    k_gemm<192,64,3><<<(NN + 127) / 128, 256, 0, stream>>>(nfeats, efeats, src, dst, eperm,
        x1, agg2, inv, b2m, b2a, pW2a, nullptr, nullptr, out);
}

// Round 3
// 549.555 us; speedup vs baseline: 2.1747x; 2.0202x over previous
//
#include <hip/hip_runtime.h>
#include <hip/hip_bf16.h>

#define NN 100000
#define EE 1600000
#define NB_SCAN 391   // (NN+255)/256

typedef __attribute__((ext_vector_type(8))) short bf16x8;
typedef __attribute__((ext_vector_type(4))) float f32x4;
typedef __attribute__((ext_vector_type(4))) unsigned int u32x4;
typedef __attribute__((ext_vector_type(2))) unsigned int u32x2;

__device__ __forceinline__ unsigned int f2bf(float x) {
    union { float f; unsigned int u; } v; v.f = x;
    return (v.u + 0x7fffu + ((v.u >> 16) & 1u)) >> 16;
}
__device__ __forceinline__ unsigned int pack2(float a, float b) {
    return f2bf(a) | (f2bf(b) << 16);
}
__device__ __forceinline__ float bf2f(unsigned short s) {
    unsigned int u = ((unsigned int)s) << 16;
    return __builtin_bit_cast(float, u);
}

// ---------------- CSR build: count -> exclusive scan -> scatter ----------------

__global__ void k_count(const int* __restrict__ dst, int* __restrict__ cnt) {
    int e = blockIdx.x * 256 + threadIdx.x;
    if (e < EE) atomicAdd(&cnt[dst[e]], 1);
}

__global__ void k_scan1(const int* __restrict__ cnt, int* __restrict__ offs,
                        int* __restrict__ part) {
    __shared__ int s[256];
    const int t = threadIdx.x;
    const int i = blockIdx.x * 256 + t;
    int v = (i < NN) ? cnt[i] : 0;
    s[t] = v; __syncthreads();
    for (int d = 1; d < 256; d <<= 1) {
        int o = (t >= d) ? s[t - d] : 0;
        __syncthreads();
        s[t] += o;
        __syncthreads();
    }
    if (i < NN) offs[i] = s[t] - v;            // block-local exclusive
    if (t == 255) part[blockIdx.x] = s[255];   // block total
}

__global__ void k_scan2(int* __restrict__ part) {
    __shared__ int s[512];
    const int t = threadIdx.x;
    int v = (t < NB_SCAN) ? part[t] : 0;
    s[t] = v; __syncthreads();
    for (int d = 1; d < 512; d <<= 1) {
        int o = (t >= d) ? s[t - d] : 0;
        __syncthreads();
        s[t] += o;
        __syncthreads();
    }
    if (t < NB_SCAN) part[t] = s[t] - v;       // exclusive over partials
}

__global__ void k_scan3(const int* __restrict__ cnt, const int* __restrict__ offs,
                        const int* __restrict__ part, int* __restrict__ offg,
                        int* __restrict__ cur, float* __restrict__ inv) {
    int i = blockIdx.x * 256 + threadIdx.x;
    if (i < NN) {
        int g = offs[i] + part[blockIdx.x];
        offg[i] = g;
        cur[i]  = g;
        int c = cnt[i];
        inv[i] = (c > 0) ? (1.0f / (float)c) : 0.0f;
    }
}

__global__ void k_scatter(const int* __restrict__ dst, const int* __restrict__ src,
                          int* __restrict__ cur,
                          int* __restrict__ eperm, int* __restrict__ srcp) {
    int e = blockIdx.x * 256 + threadIdx.x;
    if (e < EE) {
        int p = atomicAdd(&cur[dst[e]], 1);
        eperm[p] = e;
        srcp[p]  = src[e];
    }
}

// ---------------- weight pack into B-fragment lane order ----------------
// pW[((nt*KC)+kc)*64 + lane] = 8 bf16 at k = kc*32 + (lane>>4)*8 + j, n = nt*16 + (lane&15)
__global__ void k_packW(const float* __restrict__ W, u32x4* __restrict__ pW,
                        int KC, int NT, int NOUT) {
    int g = blockIdx.x * 256 + threadIdx.x;
    if (g >= NT * KC * 64) return;
    int lane = g & 63;
    int rest = g >> 6;
    int kc = rest % KC;
    int nt = rest / KC;
    int k0 = kc * 32 + ((lane >> 4) << 3);
    int n  = nt * 16 + (lane & 15);
    u32x4 u;
    #pragma unroll
    for (int t = 0; t < 4; ++t)
        u[t] = pack2(W[(k0 + 2 * t) * NOUT + n], W[(k0 + 2 * t + 1) * NOUT + n]);
    pW[g] = u;
}

// ---------------- node-centric segmented mean over CSR ----------------
// One wave per node v; lanes: s = lane>>4 (sub-edge 0..3), c = lane&15 (16B chunk).
// CASE 0: eaggm[v] = inv[v] * sum efeats[eperm[j]]   (64 f32 in,  64 bf16 out)
// CASE 1: xaggm1[v]= inv[v] * sum nfeats[srcp[j]]    (64 f32 in,  64 bf16 out)
// CASE 2: xaggm2[v]= inv[v] * sum x1[srcp[j]]        (128 bf16 in,128 bf16 out)
template<int CASE>
__global__ __launch_bounds__(256)
void k_agg(const float* __restrict__ fsrc, const unsigned short* __restrict__ bsrc,
           const int* __restrict__ idx,
           const int* __restrict__ offg, const int* __restrict__ cnt,
           const float* __restrict__ inv, unsigned short* __restrict__ outb)
{
    const int v = blockIdx.x * 4 + (threadIdx.x >> 6);
    if (v >= NN) return;
    const int lane = threadIdx.x & 63;
    const int s = lane >> 4;
    const int c = lane & 15;
    const int start = offg[v];
    const int d = cnt[v];
    constexpr int NF = (CASE == 2) ? 8 : 4;
    float acc[NF];
    #pragma unroll
    for (int q = 0; q < NF; ++q) acc[q] = 0.f;

    for (int it = 0; it < d; it += 4) {
        const int j = it + s;
        if (j < d) {
            const int r = idx[start + j];
            if constexpr (CASE == 2) {
                bf16x8 u = *(const bf16x8*)(bsrc + (size_t)r * 128 + c * 8);
                #pragma unroll
                for (int q = 0; q < 8; ++q) acc[q] += bf2f((unsigned short)u[q]);
            } else {
                f32x4 u = *(const f32x4*)(fsrc + (size_t)r * 64 + c * 4);
                #pragma unroll
                for (int q = 0; q < 4; ++q) acc[q] += u[q];
            }
        }
    }
    #pragma unroll
    for (int q = 0; q < NF; ++q) {
        acc[q] += __shfl_xor(acc[q], 16);
        acc[q] += __shfl_xor(acc[q], 32);
    }
    if (s == 0) {
        const float iv = inv[v];
        if constexpr (CASE == 2) {
            u32x4 o;
            #pragma unroll
            for (int t = 0; t < 4; ++t) o[t] = pack2(acc[2*t] * iv, acc[2*t+1] * iv);
            *(u32x4*)(outb + (size_t)v * 128 + c * 8) = o;
        } else {
            u32x2 o;
            o[0] = pack2(acc[0] * iv, acc[1] * iv);
            o[1] = pack2(acc[2] * iv, acc[3] * iv);
            *(u32x2*)(outb + (size_t)v * 64 + c * 4) = o;
        }
    }
}

// ---------------- node GEMM: out = act([in0 | in1] @ W + bias) ----------------
// A = [in0 (D0 cols) | in1 (K-D0 cols)], M=NN. in0 f32 (IN0F32) or bf16; in1 bf16.
// MSKB: bias *= [deg>0].  RELU / OUTF32 control epilogue.
template<int K, int D0, int NOUT, bool IN0F32, bool RELU, bool MSKB, bool OUTF32>
__global__ __launch_bounds__(256, 2)
void k_ngemm(const void* __restrict__ in0v, const unsigned short* __restrict__ in1,
             const float* __restrict__ bias, const float* __restrict__ inv,
             const u32x4* __restrict__ pW, void* __restrict__ outv)
{
    constexpr int KC = K / 32;
    constexpr int U  = K / 8;
    constexpr int CH = K / 16;
    constexpr int D1 = K - D0;
    constexpr int NT = NOUT / 32;   // n-tiles per wave (2 waves split NOUT)

    __shared__ u32x4 A4[128 * U];

    const int tid  = threadIdx.x;
    const int lane = tid & 63;
    const int w    = tid >> 6;
    const int tileM = blockIdx.x * 128;

    // ---- stage A tile (128 rows x K) into swizzled LDS as bf16 ----
    for (int idx = tid; idx < 128 * CH; idx += 256) {
        const int row = idx / CH;
        const int c   = idx - row * CH;
        const int k0  = c * 16;
        const int gr  = tileM + row;
        u32x4 u0, u1;
        u0[0]=u0[1]=u0[2]=u0[3]=0u; u1[0]=u1[1]=u1[2]=u1[3]=0u;
        if (gr < NN) {
            if (k0 < D0) {
                if constexpr (IN0F32) {
                    const f32x4* pv = (const f32x4*)((const float*)in0v + (size_t)gr * D0 + k0);
                    f32x4 f0 = pv[0], f1 = pv[1], f2 = pv[2], f3 = pv[3];
                    u0[0]=pack2(f0[0],f0[1]); u0[1]=pack2(f0[2],f0[3]);
                    u0[2]=pack2(f1[0],f1[1]); u0[3]=pack2(f1[2],f1[3]);
                    u1[0]=pack2(f2[0],f2[1]); u1[1]=pack2(f2[2],f2[3]);
                    u1[2]=pack2(f3[0],f3[1]); u1[3]=pack2(f3[2],f3[3]);
                } else {
                    const u32x4* p = (const u32x4*)((const unsigned short*)in0v + (size_t)gr * D0 + k0);
                    u0 = p[0]; u1 = p[1];
                }
            } else {
                const u32x4* p = (const u32x4*)(in1 + (size_t)gr * D1 + (k0 - D0));
                u0 = p[0]; u1 = p[1];
            }
        }
        const int q = k0 >> 3;
        const int s = row & 7;
        A4[row * U + ((q    ) ^ s)] = u0;
        A4[row * U + ((q + 1) ^ s)] = u1;
    }
    __syncthreads();

    // ---- MFMA: wave tile = 64 rows x (NT*16) cols ----
    const int rowBase = (w >> 1) * 64;
    const int ctBase  = (w & 1) * NT;
    const int lrow    = lane & 15;
    const int kq      = lane >> 4;

    f32x4 acc[4][NT];
    #pragma unroll
    for (int mt = 0; mt < 4; ++mt)
        #pragma unroll
        for (int nt = 0; nt < NT; ++nt)
            #pragma unroll
            for (int q = 0; q < 4; ++q) acc[mt][nt][q] = 0.f;

    for (int kc = 0; kc < KC; ++kc) {
        bf16x8 a[4];
        #pragma unroll
        for (int mt = 0; mt < 4; ++mt) {
            const int row = rowBase + mt * 16 + lrow;
            a[mt] = __builtin_bit_cast(bf16x8, A4[row * U + ((kc * 4 + kq) ^ (row & 7))]);
        }
        #pragma unroll
        for (int nt = 0; nt < NT; ++nt) {
            bf16x8 b = __builtin_bit_cast(bf16x8,
                        pW[(size_t)((ctBase + nt) * KC + kc) * 64 + lane]);
            #pragma unroll
            for (int mt = 0; mt < 4; ++mt)
                acc[mt][nt] = __builtin_amdgcn_mfma_f32_16x16x32_bf16(a[mt], b, acc[mt][nt], 0, 0, 0);
        }
    }

    // ---- epilogue ----
    float bb[NT];
    #pragma unroll
    for (int nt = 0; nt < NT; ++nt) bb[nt] = bias[(ctBase + nt) * 16 + lrow];

    #pragma unroll
    for (int mt = 0; mt < 4; ++mt) {
        #pragma unroll
        for (int j = 0; j < 4; ++j) {
            const int gr = tileM + rowBase + mt * 16 + kq * 4 + j;
            if (gr < NN) {
                float bscale = 1.f;
                if constexpr (MSKB) bscale = (inv[gr] > 0.f) ? 1.f : 0.f;
                #pragma unroll
                for (int nt = 0; nt < NT; ++nt) {
                    float v = acc[mt][nt][j] + bb[nt] * bscale;
                    if constexpr (RELU) v = fmaxf(v, 0.f);
                    const int col = (ctBase + nt) * 16 + lrow;
                    if constexpr (OUTF32)
                        ((float*)outv)[(size_t)gr * NOUT + col] = v;
                    else
                        ((unsigned short*)outv)[(size_t)gr * NOUT + col] = (unsigned short)f2bf(v);
                }
            }
        }
    }
}

extern "C" void kernel_launch(void* const* d_in, const int* in_sizes, int n_in,
                              void* d_out, int out_size, void* d_ws, size_t ws_size,
                              hipStream_t stream) {
    const float* nfeats = (const float*)d_in[0];
    const float* efeats = (const float*)d_in[1];
    const int*   src    = (const int*)d_in[2];
    const int*   dst    = (const int*)d_in[3];
    const float* W1m = (const float*)d_in[4];
    const float* b1m = (const float*)d_in[5];
    const float* W1a = (const float*)d_in[6];
    const float* b1a = (const float*)d_in[7];
    const float* W2m = (const float*)d_in[8];
    const float* b2m = (const float*)d_in[9];
    const float* W2a = (const float*)d_in[10];
    const float* b2a = (const float*)d_in[11];
    float* out = (float*)d_out;

    char* ws = (char*)d_ws;
    unsigned short* eaggm  = (unsigned short*)(ws + 0);         // N*64 bf16  = 12.8 MB
    unsigned short* xaggm1 = (unsigned short*)(ws + 12800000);  // N*64 bf16  = 12.8 MB
    unsigned short* h1     = (unsigned short*)(ws + 25600000);  // N*128 bf16 = 25.6 MB
    unsigned short* xaggm2 = (unsigned short*)(ws + 12800000);  // overlays xaggm1+h1 (dead by then)
    unsigned short* x1     = (unsigned short*)(ws + 51200000);  // N*128 bf16 = 25.6 MB
    int*            eperm  = (int*)(ws + 76800000);             // E int = 6.4 MB
    int*            srcp   = (int*)(ws + 83200000);             // E int = 6.4 MB
    unsigned short* h2     = (unsigned short*)(ws + 76800000);  // overlays eperm+srcp (dead by then)
    int*            cnt    = (int*)(ws + 89600000);             // N int
    int*            offs   = (int*)(ws + 90000000);             // N int
    int*            offg   = (int*)(ws + 90400000);             // N int
    int*            cur    = (int*)(ws + 90800000);             // N int
    int*            part   = (int*)(ws + 91200000);             // 512 int
    float*          inv    = (float*)(ws + 91202048);           // N f32
    u32x4* pW1m = (u32x4*)(ws + 91602048);                      // 32 KB
    u32x4* pW1a = (u32x4*)(ws + 91634816);                      // 48 KB
    u32x4* pW2m = (u32x4*)(ws + 91683968);                      // 24 KB
    u32x4* pW2a = (u32x4*)(ws + 91708544);                      // 24 KB

    hipMemsetAsync(cnt, 0, (size_t)NN * 4, stream);

    k_packW<<<(2048 + 255) / 256, 256, 0, stream>>>(W1m, pW1m, 4, 8, 128);
    k_packW<<<(3072 + 255) / 256, 256, 0, stream>>>(W1a, pW1a, 6, 8, 128);
    k_packW<<<(1536 + 255) / 256, 256, 0, stream>>>(W2m, pW2m, 6, 4, 64);
    k_packW<<<(1536 + 255) / 256, 256, 0, stream>>>(W2a, pW2a, 6, 4, 64);

    // CSR bucketing by dst
    k_count  <<<(EE + 255) / 256, 256, 0, stream>>>(dst, cnt);
    k_scan1  <<<NB_SCAN, 256, 0, stream>>>(cnt, offs, part);
    k_scan2  <<<1, 512, 0, stream>>>(part);
    k_scan3  <<<NB_SCAN, 256, 0, stream>>>(cnt, offs, part, offg, cur, inv);
    k_scatter<<<(EE + 255) / 256, 256, 0, stream>>>(dst, src, cur, eperm, srcp);

    const int NBAGG = NN / 4;  // 25000 blocks, 1 wave per node

    // eaggm = inv * segsum(efeats)   [shared by both layers]
    k_agg<0><<<NBAGG, 256, 0, stream>>>(efeats, nullptr, eperm, offg, cnt, inv, eaggm);
    // xaggm1 = inv * segsum(nfeats[src])
    k_agg<1><<<NBAGG, 256, 0, stream>>>(nfeats, nullptr, srcp, offg, cnt, inv, xaggm1);

    const int NBG = (NN + 127) / 128;  // 782

    // h1 = [xaggm1 | eaggm] @ W1m + b1m*msk          (K=128, NOUT=128, bf16)
    k_ngemm<128, 64, 128, false, false, true, false><<<NBG, 256, 0, stream>>>(
        xaggm1, eaggm, b1m, inv, pW1m, h1);
    // x1 = relu([nfeats | h1] @ W1a + b1a)           (K=192, NOUT=128, bf16)
    k_ngemm<192, 64, 128, true, true, false, false><<<NBG, 256, 0, stream>>>(
        nfeats, h1, b1a, inv, pW1a, x1);
    // xaggm2 = inv * segsum(x1[src])
    k_agg<2><<<NBAGG, 256, 0, stream>>>(nullptr, x1, srcp, offg, cnt, inv, xaggm2);
    // h2 = [xaggm2 | eaggm] @ W2m + b2m*msk          (K=192, NOUT=64, bf16)
    k_ngemm<192, 128, 64, false, false, true, false><<<NBG, 256, 0, stream>>>(
        xaggm2, eaggm, b2m, inv, pW2m, h2);
    // out = relu([x1 | h2] @ W2a + b2a)              (K=192, NOUT=64, f32)
    k_ngemm<192, 128, 64, false, true, false, true><<<NBG, 256, 0, stream>>>(
        x1, h2, b2a, inv, pW2a, out);
}

// Round 4
// 497.894 us; speedup vs baseline: 2.4003x; 1.1038x over previous
//
#include <hip/hip_runtime.h>
#include <hip/hip_bf16.h>

#define NN 100000
#define EE 1600000
#define NB_SCAN 391   // (NN+255)/256

typedef __attribute__((ext_vector_type(8))) short bf16x8;
typedef __attribute__((ext_vector_type(4))) float f32x4;
typedef __attribute__((ext_vector_type(4))) unsigned int u32x4;
typedef __attribute__((ext_vector_type(2))) unsigned int u32x2;

__device__ __forceinline__ unsigned int f2bf(float x) {
    union { float f; unsigned int u; } v; v.f = x;
    return (v.u + 0x7fffu + ((v.u >> 16) & 1u)) >> 16;
}
__device__ __forceinline__ unsigned int pack2(float a, float b) {
    return f2bf(a) | (f2bf(b) << 16);
}
__device__ __forceinline__ float bf2f(unsigned short s) {
    unsigned int u = ((unsigned int)s) << 16;
    return __builtin_bit_cast(float, u);
}

// ---------------- CSR build: zero -> count -> exclusive scan -> scatter ----------------

__global__ void k_zero(int* __restrict__ cnt) {
    int i = blockIdx.x * 256 + threadIdx.x;
    if (i < NN) cnt[i] = 0;
}

__global__ void k_count(const int* __restrict__ dst, int* __restrict__ cnt) {
    int e = blockIdx.x * 256 + threadIdx.x;
    if (e < EE) atomicAdd(&cnt[dst[e]], 1);
}

__global__ void k_scan1(const int* __restrict__ cnt, int* __restrict__ offs,
                        int* __restrict__ part) {
    __shared__ int s[256];
    const int t = threadIdx.x;
    const int i = blockIdx.x * 256 + t;
    int v = (i < NN) ? cnt[i] : 0;
    s[t] = v; __syncthreads();
    for (int d = 1; d < 256; d <<= 1) {
        int o = (t >= d) ? s[t - d] : 0;
        __syncthreads();
        s[t] += o;
        __syncthreads();
    }
    if (i < NN) offs[i] = s[t] - v;            // block-local exclusive
    if (t == 255) part[blockIdx.x] = s[255];   // block total
}

__global__ void k_scan2(int* __restrict__ part) {
    __shared__ int s[512];
    const int t = threadIdx.x;
    int v = (t < NB_SCAN) ? part[t] : 0;
    s[t] = v; __syncthreads();
    for (int d = 1; d < 512; d <<= 1) {
        int o = (t >= d) ? s[t - d] : 0;
        __syncthreads();
        s[t] += o;
        __syncthreads();
    }
    if (t < NB_SCAN) part[t] = s[t] - v;       // exclusive over partials
}

__global__ void k_scan3(const int* __restrict__ cnt, const int* __restrict__ offs,
                        const int* __restrict__ part, int* __restrict__ offg,
                        int* __restrict__ cur, float* __restrict__ inv) {
    int i = blockIdx.x * 256 + threadIdx.x;
    if (i < NN) {
        int g = offs[i] + part[blockIdx.x];
        offg[i] = g;
        cur[i]  = g;
        int c = cnt[i];
        inv[i] = (c > 0) ? (1.0f / (float)c) : 0.0f;
    }
}

__global__ void k_scatter(const int* __restrict__ dst, const int* __restrict__ src,
                          int* __restrict__ cur,
                          int* __restrict__ eperm, int* __restrict__ srcp) {
    int e = blockIdx.x * 256 + threadIdx.x;
    if (e < EE) {
        int p = atomicAdd(&cur[dst[e]], 1);
        eperm[p] = e;
        srcp[p]  = src[e];
    }
}

// ---------------- weight pack into B-fragment lane order ----------------
// pW[((nt*KC)+kc)*64 + lane] = 8 bf16 at k = kc*32 + (lane>>4)*8 + j, n = nt*16 + (lane&15)
__global__ void k_packW(const float* __restrict__ W, u32x4* __restrict__ pW,
                        int KC, int NT, int NOUT) {
    int g = blockIdx.x * 256 + threadIdx.x;
    if (g >= NT * KC * 64) return;
    int lane = g & 63;
    int rest = g >> 6;
    int kc = rest % KC;
    int nt = rest / KC;
    int k0 = kc * 32 + ((lane >> 4) << 3);
    int n  = nt * 16 + (lane & 15);
    u32x4 u;
    #pragma unroll
    for (int t = 0; t < 4; ++t)
        u[t] = pack2(W[(k0 + 2 * t) * NOUT + n], W[(k0 + 2 * t + 1) * NOUT + n]);
    pW[g] = u;
}

// ---------------- fused layer-1 segmented mean over CSR ----------------
// One wave per node v; lanes: s = lane>>4 (sub-edge 0..3), c = lane&15 (16B chunk).
// eaggm[v]  = inv[v] * sum efeats[eperm[j]]   (HBM stream, 410 MB)
// xaggm1[v] = inv[v] * sum nfeats[srcp[j]]    (cache-served gather)
__global__ __launch_bounds__(256)
void k_agg01(const float* __restrict__ efeats, const float* __restrict__ nfeats,
             const int* __restrict__ eperm, const int* __restrict__ srcp,
             const int* __restrict__ offg, const int* __restrict__ cnt,
             const float* __restrict__ inv,
             unsigned short* __restrict__ eaggm, unsigned short* __restrict__ xaggm1)
{
    const int v = blockIdx.x * 4 + (threadIdx.x >> 6);
    if (v >= NN) return;
    const int lane = threadIdx.x & 63;
    const int s = lane >> 4;
    const int c = lane & 15;
    const int start = offg[v];
    const int d = cnt[v];
    float ae[4], ax[4];
    #pragma unroll
    for (int q = 0; q < 4; ++q) { ae[q] = 0.f; ax[q] = 0.f; }

    for (int it = 0; it < d; it += 4) {
        const int j = it + s;
        if (j < d) {
            const int e = eperm[start + j];
            const int r = srcp[start + j];
            f32x4 ue = *(const f32x4*)(efeats + (size_t)e * 64 + c * 4);
            f32x4 ux = *(const f32x4*)(nfeats + (size_t)r * 64 + c * 4);
            #pragma unroll
            for (int q = 0; q < 4; ++q) { ae[q] += ue[q]; ax[q] += ux[q]; }
        }
    }
    #pragma unroll
    for (int q = 0; q < 4; ++q) {
        ae[q] += __shfl_xor(ae[q], 16);
        ae[q] += __shfl_xor(ae[q], 32);
        ax[q] += __shfl_xor(ax[q], 16);
        ax[q] += __shfl_xor(ax[q], 32);
    }
    if (s == 0) {
        const float iv = inv[v];
        u32x2 oe, ox;
        oe[0] = pack2(ae[0] * iv, ae[1] * iv);
        oe[1] = pack2(ae[2] * iv, ae[3] * iv);
        ox[0] = pack2(ax[0] * iv, ax[1] * iv);
        ox[1] = pack2(ax[2] * iv, ax[3] * iv);
        *(u32x2*)(eaggm  + (size_t)v * 64 + c * 4) = oe;
        *(u32x2*)(xaggm1 + (size_t)v * 64 + c * 4) = ox;
    }
}

// ---------------- layer-2 segmented mean: xaggm2 = inv * segsum(x1[src]) ----------------
__global__ __launch_bounds__(256)
void k_agg2(const unsigned short* __restrict__ bsrc, const int* __restrict__ idx,
            const int* __restrict__ offg, const int* __restrict__ cnt,
            const float* __restrict__ inv, unsigned short* __restrict__ outb)
{
    const int v = blockIdx.x * 4 + (threadIdx.x >> 6);
    if (v >= NN) return;
    const int lane = threadIdx.x & 63;
    const int s = lane >> 4;
    const int c = lane & 15;
    const int start = offg[v];
    const int d = cnt[v];
    float acc[8];
    #pragma unroll
    for (int q = 0; q < 8; ++q) acc[q] = 0.f;

    for (int it = 0; it < d; it += 4) {
        const int j = it + s;
        if (j < d) {
            const int r = idx[start + j];
            bf16x8 u = *(const bf16x8*)(bsrc + (size_t)r * 128 + c * 8);
            #pragma unroll
            for (int q = 0; q < 8; ++q) acc[q] += bf2f((unsigned short)u[q]);
        }
    }
    #pragma unroll
    for (int q = 0; q < 8; ++q) {
        acc[q] += __shfl_xor(acc[q], 16);
        acc[q] += __shfl_xor(acc[q], 32);
    }
    if (s == 0) {
        const float iv = inv[v];
        u32x4 o;
        #pragma unroll
        for (int t = 0; t < 4; ++t) o[t] = pack2(acc[2*t] * iv, acc[2*t+1] * iv);
        *(u32x4*)(outb + (size_t)v * 128 + c * 8) = o;
    }
}

// ---------------- node GEMM: out = act([in0 | in1] @ W + bias) ----------------
// A = [in0 (D0 cols) | in1 (K-D0 cols)], M=NN. in0 f32 (IN0F32) or bf16; in1 bf16.
// MSKB: bias *= [deg>0].  RELU / OUTF32 control epilogue.
template<int K, int D0, int NOUT, bool IN0F32, bool RELU, bool MSKB, bool OUTF32>
__global__ __launch_bounds__(256, 2)
void k_ngemm(const void* __restrict__ in0v, const unsigned short* __restrict__ in1,
             const float* __restrict__ bias, const float* __restrict__ inv,
             const u32x4* __restrict__ pW, void* __restrict__ outv)
{
    constexpr int KC = K / 32;
    constexpr int U  = K / 8;
    constexpr int CH = K / 16;
    constexpr int D1 = K - D0;
    constexpr int NT = NOUT / 32;   // n-tiles per wave (2 waves split NOUT)

    __shared__ u32x4 A4[128 * U];

    const int tid  = threadIdx.x;
    const int lane = tid & 63;
    const int w    = tid >> 6;
    const int tileM = blockIdx.x * 128;

    // ---- stage A tile (128 rows x K) into swizzled LDS as bf16 ----
    for (int idx = tid; idx < 128 * CH; idx += 256) {
        const int row = idx / CH;
        const int c   = idx - row * CH;
        const int k0  = c * 16;
        const int gr  = tileM + row;
        u32x4 u0, u1;
        u0[0]=u0[1]=u0[2]=u0[3]=0u; u1[0]=u1[1]=u1[2]=u1[3]=0u;
        if (gr < NN) {
            if (k0 < D0) {
                if constexpr (IN0F32) {
                    const f32x4* pv = (const f32x4*)((const float*)in0v + (size_t)gr * D0 + k0);
                    f32x4 f0 = pv[0], f1 = pv[1], f2 = pv[2], f3 = pv[3];
                    u0[0]=pack2(f0[0],f0[1]); u0[1]=pack2(f0[2],f0[3]);
                    u0[2]=pack2(f1[0],f1[1]); u0[3]=pack2(f1[2],f1[3]);
                    u1[0]=pack2(f2[0],f2[1]); u1[1]=pack2(f2[2],f2[3]);
                    u1[2]=pack2(f3[0],f3[1]); u1[3]=pack2(f3[2],f3[3]);
                } else {
                    const u32x4* p = (const u32x4*)((const unsigned short*)in0v + (size_t)gr * D0 + k0);
                    u0 = p[0]; u1 = p[1];
                }
            } else {
                const u32x4* p = (const u32x4*)(in1 + (size_t)gr * D1 + (k0 - D0));
                u0 = p[0]; u1 = p[1];
            }
        }
        const int q = k0 >> 3;
        const int s = row & 7;
        A4[row * U + ((q    ) ^ s)] = u0;
        A4[row * U + ((q + 1) ^ s)] = u1;
    }
    __syncthreads();

    // ---- MFMA: wave tile = 64 rows x (NT*16) cols ----
    const int rowBase = (w >> 1) * 64;
    const int ctBase  = (w & 1) * NT;
    const int lrow    = lane & 15;
    const int kq      = lane >> 4;

    f32x4 acc[4][NT];
    #pragma unroll
    for (int mt = 0; mt < 4; ++mt)
        #pragma unroll
        for (int nt = 0; nt < NT; ++nt)
            #pragma unroll
            for (int q = 0; q < 4; ++q) acc[mt][nt][q] = 0.f;

    for (int kc = 0; kc < KC; ++kc) {
        bf16x8 a[4];
        #pragma unroll
        for (int mt = 0; mt < 4; ++mt) {
            const int row = rowBase + mt * 16 + lrow;
            a[mt] = __builtin_bit_cast(bf16x8, A4[row * U + ((kc * 4 + kq) ^ (row & 7))]);
        }
        #pragma unroll
        for (int nt = 0; nt < NT; ++nt) {
            bf16x8 b = __builtin_bit_cast(bf16x8,
                        pW[(size_t)((ctBase + nt) * KC + kc) * 64 + lane]);
            #pragma unroll
            for (int mt = 0; mt < 4; ++mt)
                acc[mt][nt] = __builtin_amdgcn_mfma_f32_16x16x32_bf16(a[mt], b, acc[mt][nt], 0, 0, 0);
        }
    }

    // ---- epilogue ----
    float bb[NT];
    #pragma unroll
    for (int nt = 0; nt < NT; ++nt) bb[nt] = bias[(ctBase + nt) * 16 + lrow];

    #pragma unroll
    for (int mt = 0; mt < 4; ++mt) {
        #pragma unroll
        for (int j = 0; j < 4; ++j) {
            const int gr = tileM + rowBase + mt * 16 + kq * 4 + j;
            if (gr < NN) {
                float bscale = 1.f;
                if constexpr (MSKB) bscale = (inv[gr] > 0.f) ? 1.f : 0.f;
                #pragma unroll
                for (int nt = 0; nt < NT; ++nt) {
                    float v = acc[mt][nt][j] + bb[nt] * bscale;
                    if constexpr (RELU) v = fmaxf(v, 0.f);
                    const int col = (ctBase + nt) * 16 + lrow;
                    if constexpr (OUTF32)
                        ((float*)outv)[(size_t)gr * NOUT + col] = v;
                    else
                        ((unsigned short*)outv)[(size_t)gr * NOUT + col] = (unsigned short)f2bf(v);
                }
            }
        }
    }
}

extern "C" void kernel_launch(void* const* d_in, const int* in_sizes, int n_in,
                              void* d_out, int out_size, void* d_ws, size_t ws_size,
                              hipStream_t stream) {
    const float* nfeats = (const float*)d_in[0];
    const float* efeats = (const float*)d_in[1];
    const int*   src    = (const int*)d_in[2];
    const int*   dst    = (const int*)d_in[3];
    const float* W1m = (const float*)d_in[4];
    const float* b1m = (const float*)d_in[5];
    const float* W1a = (const float*)d_in[6];
    const float* b1a = (const float*)d_in[7];
    const float* W2m = (const float*)d_in[8];
    const float* b2m = (const float*)d_in[9];
    const float* W2a = (const float*)d_in[10];
    const float* b2a = (const float*)d_in[11];
    float* out = (float*)d_out;

    char* ws = (char*)d_ws;
    unsigned short* eaggm  = (unsigned short*)(ws + 0);         // N*64 bf16  = 12.8 MB
    unsigned short* xaggm1 = (unsigned short*)(ws + 12800000);  // N*64 bf16  = 12.8 MB
    unsigned short* h1     = (unsigned short*)(ws + 25600000);  // N*128 bf16 = 25.6 MB
    unsigned short* xaggm2 = (unsigned short*)(ws + 12800000);  // overlays xaggm1+h1 (dead by then)
    unsigned short* x1     = (unsigned short*)(ws + 51200000);  // N*128 bf16 = 25.6 MB
    int*            eperm  = (int*)(ws + 76800000);             // E int = 6.4 MB
    int*            srcp   = (int*)(ws + 83200000);             // E int = 6.4 MB
    unsigned short* h2     = (unsigned short*)(ws + 76800000);  // overlays eperm+srcp (dead by then)
    int*            cnt    = (int*)(ws + 89600000);             // N int
    int*            offs   = (int*)(ws + 90000000);             // N int
    int*            offg   = (int*)(ws + 90400000);             // N int
    int*            cur    = (int*)(ws + 90800000);             // N int
    int*            part   = (int*)(ws + 91200000);             // 512 int
    float*          inv    = (float*)(ws + 91202048);           // N f32
    u32x4* pW1m = (u32x4*)(ws + 91602048);                      // 32 KB
    u32x4* pW1a = (u32x4*)(ws + 91634816);                      // 48 KB
    u32x4* pW2m = (u32x4*)(ws + 91683968);                      // 24 KB
    u32x4* pW2a = (u32x4*)(ws + 91708544);                      // 24 KB

    // zero cnt with a kernel — in-graph fillBufferAligned measured 240 µs (!) in R3
    k_zero<<<NB_SCAN, 256, 0, stream>>>(cnt);

    k_packW<<<(2048 + 255) / 256, 256, 0, stream>>>(W1m, pW1m, 4, 8, 128);
    k_packW<<<(3072 + 255) / 256, 256, 0, stream>>>(W1a, pW1a, 6, 8, 128);
    k_packW<<<(1536 + 255) / 256, 256, 0, stream>>>(W2m, pW2m, 6, 4, 64);
    k_packW<<<(1536 + 255) / 256, 256, 0, stream>>>(W2a, pW2a, 6, 4, 64);

    // CSR bucketing by dst
    k_count  <<<(EE + 255) / 256, 256, 0, stream>>>(dst, cnt);
    k_scan1  <<<NB_SCAN, 256, 0, stream>>>(cnt, offs, part);
    k_scan2  <<<1, 512, 0, stream>>>(part);
    k_scan3  <<<NB_SCAN, 256, 0, stream>>>(cnt, offs, part, offg, cur, inv);
    k_scatter<<<(EE + 255) / 256, 256, 0, stream>>>(dst, src, cur, eperm, srcp);

    const int NBAGG = NN / 4;  // 25000 blocks, 1 wave per node

    // fused: eaggm = inv*segsum(efeats), xaggm1 = inv*segsum(nfeats[src])
    k_agg01<<<NBAGG, 256, 0, stream>>>(efeats, nfeats, eperm, srcp, offg, cnt, inv,
                                       eaggm, xaggm1);

    const int NBG = (NN + 127) / 128;  // 782

    // h1 = [xaggm1 | eaggm] @ W1m + b1m*msk          (K=128, NOUT=128, bf16)
    k_ngemm<128, 64, 128, false, false, true, false><<<NBG, 256, 0, stream>>>(
        xaggm1, eaggm, b1m, inv, pW1m, h1);
    // x1 = relu([nfeats | h1] @ W1a + b1a)           (K=192, NOUT=128, bf16)
    k_ngemm<192, 64, 128, true, true, false, false><<<NBG, 256, 0, stream>>>(
        nfeats, h1, b1a, inv, pW1a, x1);
    // xaggm2 = inv * segsum(x1[src])
    k_agg2<<<NBAGG, 256, 0, stream>>>(x1, srcp, offg, cnt, inv, xaggm2);
    // h2 = [xaggm2 | eaggm] @ W2m + b2m*msk          (K=192, NOUT=64, bf16)
    k_ngemm<192, 128, 64, false, false, true, false><<<NBG, 256, 0, stream>>>(
        xaggm2, eaggm, b2m, inv, pW2m, h2);
    // out = relu([x1 | h2] @ W2a + b2a)              (K=192, NOUT=64, f32)
    k_ngemm<192, 128, 64, false, true, false, true><<<NBG, 256, 0, stream>>>(
        x1, h2, b2a, inv, pW2a, out);
}